// Round 4
// baseline (8079.971 us; speedup 1.0000x reference)
//
#include <hip/hip_runtime.h>
#include <hip/hip_bf16.h>

typedef __hip_bfloat16 bf16;

#define B_  16
#define C_  512
#define T_  1024
#define G_  32
#define CPG 16
#define E_  1024
#define NH  8
#define CH  64
#define CT  (C_ * T_)   // 524288 elements per batch

__device__ __forceinline__ float b2f(bf16 v) { return __bfloat162float(v); }
__device__ __forceinline__ bf16  f2b(float v) { return __float2bfloat16(v); }

// ---------------------------------------------------------------------------
// K1: FiLM linear: e[b,j] = sum_i silu(emb[b,i]) * emb_w[j,i] + emb_b[j]
// grid (4, 16), block 256. e is [B, 2C] fp32.
// ---------------------------------------------------------------------------
__global__ __launch_bounds__(256) void film_kernel(
    const float* __restrict__ emb, const float* __restrict__ emb_w,
    const float* __restrict__ emb_b, float* __restrict__ e_out) {
  __shared__ float se[E_];
  int b = blockIdx.y;
  int tid = threadIdx.x;
  for (int i = tid; i < E_; i += 256) {
    float v = emb[(size_t)b * E_ + i];
    se[i] = v / (1.f + __expf(-v));  // silu
  }
  __syncthreads();
  int j = blockIdx.x * 256 + tid;  // 0..1023 (= 2C)
  float acc = emb_b[j];
  for (int i = 0; i < E_; i++) acc += se[i] * emb_w[(size_t)j * E_ + i];
  e_out[b * (2 * C_) + j] = acc;
}

// ---------------------------------------------------------------------------
// K2: GroupNorm stats. One block per (b,g); group data is 16384 contiguous f32.
// ---------------------------------------------------------------------------
__global__ __launch_bounds__(256) void gn_stats_kernel(
    const float* __restrict__ x, float* __restrict__ mean_buf,
    float* __restrict__ rstd_buf) {
  int bg = blockIdx.x;  // b*G + g
  const float* base = x + (size_t)bg * (CPG * T_);
  int tid = threadIdx.x;
  float s = 0.f, sq = 0.f;
  for (int i = tid; i < CPG * T_; i += 256) {
    float v = base[i];
    s += v;
    sq += v * v;
  }
  for (int off = 32; off > 0; off >>= 1) {
    s += __shfl_down(s, off, 64);
    sq += __shfl_down(sq, off, 64);
  }
  __shared__ float ss[4], ssq[4];
  int wid = tid >> 6, lane = tid & 63;
  if (lane == 0) { ss[wid] = s; ssq[wid] = sq; }
  __syncthreads();
  if (tid == 0) {
    float S = ss[0] + ss[1] + ss[2] + ss[3];
    float Q = ssq[0] + ssq[1] + ssq[2] + ssq[3];
    const float inv_n = 1.f / (CPG * T_);
    float m = S * inv_n;
    float var = Q * inv_n - m * m;
    mean_buf[bg] = m;
    rstd_buf[bg] = rsqrtf(fmaxf(var, 0.f) + 1e-5f);
  }
}

// ---------------------------------------------------------------------------
// K3: normalize + FiLM -> h (bf16). One elem/thread. Chunked: NB batches
// starting at b0; h is chunk-local, x/e/mean/rstd global.
// ---------------------------------------------------------------------------
__global__ __launch_bounds__(256) void norm_film_kernel(
    const float* __restrict__ x, const float* __restrict__ mean_buf,
    const float* __restrict__ rstd_buf, const float* __restrict__ gamma,
    const float* __restrict__ beta, const float* __restrict__ e_buf,
    bf16* __restrict__ h, int b0) {
  int idx = blockIdx.x * 256 + threadIdx.x;  // < NB*CT (chunk-local)
  int bc = idx >> 10;        // bl*C + c
  int c = bc & (C_ - 1);
  int bl = bc >> 9;
  int b = b0 + bl;
  int g = c >> 4;
  float m = mean_buf[b * G_ + g];
  float r = rstd_buf[b * G_ + g];
  float sc = e_buf[b * 2 * C_ + c];
  float sh = e_buf[b * 2 * C_ + C_ + c];
  size_t gidx = (size_t)b0 * CT + idx;
  float v = (x[gidx] - m) * r * gamma[c] + beta[c];
  v = v * (1.f + sc) + sh;
  h[idx] = f2b(v);
}

// ---------------------------------------------------------------------------
// K4: QKV GEMM: qkv[b,o,t] = sum_c qkv_w[o,c]*h[b,c,t] + qkv_b[o]
// 64x64 tile, 256 threads, 4x4 per thread, K-step 16.
// o = hd*192 + r; r<64 -> q, <128 -> k, else v. q,k pre-scaled by 64^-0.25.
// q,k,v chunk-local [bhl][ch][t] bf16.
// ---------------------------------------------------------------------------
__global__ __launch_bounds__(256) void qkv_gemm_kernel(
    const bf16* __restrict__ h, const float* __restrict__ qkv_w,
    const float* __restrict__ qkv_b, bf16* __restrict__ qb,
    bf16* __restrict__ kb, bf16* __restrict__ vb) {
  __shared__ float Ws[16][65];  // [c_local][o_local]
  __shared__ float Hs[16][65];  // [c_local][t_local]
  int bl = blockIdx.z;
  int o0 = blockIdx.y * 64;
  int t0 = blockIdx.x * 64;
  int tid = threadIdx.x;
  int tx = tid & 15, ty = tid >> 4;
  float acc[4][4] = {};
  const bf16* hb = h + (size_t)bl * CT;
  for (int k0 = 0; k0 < C_; k0 += 16) {
    int cl = tid & 15, ol = tid >> 4;
    for (int p = 0; p < 4; p++)
      Ws[cl][ol + 16 * p] = qkv_w[(size_t)(o0 + ol + 16 * p) * C_ + k0 + cl];
    int tl = tid & 63, ch = tid >> 6;
    for (int p = 0; p < 4; p++)
      Hs[ch + 4 * p][tl] = b2f(hb[(size_t)(k0 + ch + 4 * p) * T_ + t0 + tl]);
    __syncthreads();
    for (int kk = 0; kk < 16; kk++) {
      float wr[4], hr[4];
      for (int i = 0; i < 4; i++) wr[i] = Ws[kk][ty + 16 * i];
      for (int j = 0; j < 4; j++) hr[j] = Hs[kk][tx + 16 * j];
      for (int i = 0; i < 4; i++)
        for (int j = 0; j < 4; j++) acc[i][j] += wr[i] * hr[j];
    }
    __syncthreads();
  }
  const float s = 0.35355339059327373f;  // 1/sqrt(sqrt(64))
  for (int i = 0; i < 4; i++) {
    int o = o0 + ty + 16 * i;
    int hd = o / 192, r = o % 192;
    int sec = r >> 6, ch = r & 63;
    float bias = qkv_b[o];
    bf16* dst = sec == 0 ? qb : (sec == 1 ? kb : vb);
    float mul = (sec == 2) ? 1.f : s;
    size_t base = ((size_t)(bl * NH + hd) * CH + ch) * T_ + t0;
    for (int j = 0; j < 4; j++) {
      int t = tx + 16 * j;
      dst[base + t] = f2b((acc[i][j] + bias) * mul);
    }
  }
}

// ---------------------------------------------------------------------------
// K5: attention. One block = (bhl, 8 queries). Two-pass with scores in LDS.
// q,k,v chunk-local; a chunk-local [bl][C][T] bf16 (aliases h).
// ---------------------------------------------------------------------------
__global__ __launch_bounds__(256) void attn_kernel(
    const bf16* __restrict__ qb, const bf16* __restrict__ kb,
    const bf16* __restrict__ vb, bf16* __restrict__ a) {
  __shared__ float sc[8][1028];  // padded row stride
  __shared__ float qs[8][64];
  __shared__ float rinv[8];
  int bhl = blockIdx.y;  // 0..NB*8-1
  int qt = blockIdx.x;   // 0..127
  int tid = threadIdx.x;
  const size_t hbl = (size_t)bhl * CH * T_;
  for (int i = tid; i < 8 * 64; i += 256) {
    int qi = i >> 6, c = i & 63;
    qs[qi][c] = b2f(qb[hbl + (size_t)c * T_ + qt * 8 + qi]);
  }
  __syncthreads();
  int qi = tid >> 5, jj = tid & 31;
  // Phase A: scores
  for (int st = 0; st < 32; st++) {
    int j = st * 32 + jj;
    float acc = 0.f;
    const bf16* kp = kb + hbl + j;
    for (int c = 0; c < 64; c++) acc += qs[qi][c] * b2f(kp[(size_t)c * T_]);
    sc[qi][j] = acc;
  }
  __syncthreads();
  // Phase B: softmax per row (32 threads/row)
  float m = -1e30f;
  for (int st = 0; st < 32; st++) m = fmaxf(m, sc[qi][st * 32 + jj]);
  for (int off = 16; off > 0; off >>= 1) m = fmaxf(m, __shfl_xor(m, off, 32));
  float sum = 0.f;
  for (int st = 0; st < 32; st++) {
    int j = st * 32 + jj;
    float e = __expf(sc[qi][j] - m);
    sc[qi][j] = e;
    sum += e;
  }
  for (int off = 16; off > 0; off >>= 1) sum += __shfl_xor(sum, off, 32);
  if (jj == 0) rinv[qi] = 1.f / sum;
  __syncthreads();
  // Phase C: PV. thread -> (c = tid&63, rows g and g+4)
  int c = tid & 63, g = tid >> 6;
  float a0 = 0.f, a1 = 0.f;
  const bf16* vp = vb + hbl + (size_t)c * T_;
  for (int j = 0; j < T_; j++) {
    float vv = b2f(vp[j]);
    a0 += sc[g][j] * vv;
    a1 += sc[g + 4][j] * vv;
  }
  int bl = bhl >> 3, hd = bhl & 7;
  size_t ob = ((size_t)bl * C_ + hd * CH + c) * T_ + qt * 8;
  a[ob + g] = f2b(a0 * rinv[g]);
  a[ob + g + 4] = f2b(a1 * rinv[g + 4]);
}

// ---------------------------------------------------------------------------
// K6: proj GEMM + residual: out[b,o,t] = x[b,o,t] + sum_c proj_w[o,c]*a[b,c,t]
// + proj_b[o]. a chunk-local bf16; x/out global fp32.
// ---------------------------------------------------------------------------
__global__ __launch_bounds__(256) void proj_kernel(
    const bf16* __restrict__ a, const float* __restrict__ proj_w,
    const float* __restrict__ proj_b, const float* __restrict__ x,
    float* __restrict__ out, int b0) {
  __shared__ float Ws[16][65];
  __shared__ float As[16][65];
  int bl = blockIdx.z;
  int b = b0 + bl;
  int o0 = blockIdx.y * 64;
  int t0 = blockIdx.x * 64;
  int tid = threadIdx.x;
  int tx = tid & 15, ty = tid >> 4;
  float acc[4][4] = {};
  const bf16* ab = a + (size_t)bl * CT;
  for (int k0 = 0; k0 < C_; k0 += 16) {
    int cl = tid & 15, ol = tid >> 4;
    for (int p = 0; p < 4; p++)
      Ws[cl][ol + 16 * p] = proj_w[(size_t)(o0 + ol + 16 * p) * C_ + k0 + cl];
    int tl = tid & 63, ch = tid >> 6;
    for (int p = 0; p < 4; p++)
      As[ch + 4 * p][tl] = b2f(ab[(size_t)(k0 + ch + 4 * p) * T_ + t0 + tl]);
    __syncthreads();
    for (int kk = 0; kk < 16; kk++) {
      float wr[4], ar[4];
      for (int i = 0; i < 4; i++) wr[i] = Ws[kk][ty + 16 * i];
      for (int j = 0; j < 4; j++) ar[j] = As[kk][tx + 16 * j];
      for (int i = 0; i < 4; i++)
        for (int j = 0; j < 4; j++) acc[i][j] += wr[i] * ar[j];
    }
    __syncthreads();
  }
  for (int i = 0; i < 4; i++) {
    int o = o0 + ty + 16 * i;
    float bias = proj_b[o];
    for (int j = 0; j < 4; j++) {
      int t = t0 + tx + 16 * j;
      size_t idx = ((size_t)b * C_ + o) * T_ + t;
      out[idx] = x[idx] + acc[i][j] + bias;
    }
  }
}

// ---------------------------------------------------------------------------
extern "C" void kernel_launch(void* const* d_in, const int* in_sizes, int n_in,
                              void* d_out, int out_size, void* d_ws,
                              size_t ws_size, hipStream_t stream) {
  const float* x      = (const float*)d_in[0];
  const float* emb    = (const float*)d_in[1];
  const float* gamma  = (const float*)d_in[2];
  const float* beta   = (const float*)d_in[3];
  const float* emb_w  = (const float*)d_in[4];
  const float* emb_b  = (const float*)d_in[5];
  const float* qkv_w  = (const float*)d_in[6];
  const float* qkv_b  = (const float*)d_in[7];
  const float* proj_w = (const float*)d_in[8];
  const float* proj_b = (const float*)d_in[9];
  float* out = (float*)d_out;

  // Fixed small region (128 KB)
  float* e_buf    = (float*)d_ws;                 // B*2C = 16384 f32
  float* mean_buf = e_buf + B_ * 2 * C_;          // 512 f32
  float* rstd_buf = mean_buf + B_ * G_;           // 512 f32
  const size_t FIXED_BYTES = 131072;
  bf16* pool = (bf16*)((char*)d_ws + FIXED_BYTES);

  // Chunk NB batches so h + q + k + v (4 * NB MiB bf16) fits in workspace.
  size_t avail = ws_size > FIXED_BYTES ? ws_size - FIXED_BYTES : 0;
  int NB = 16;
  while (NB > 1 && (size_t)4 * NB * CT * sizeof(bf16) > avail) NB >>= 1;

  bf16* h_buf = pool;                       // also 'a' (aliased after h consumed)
  bf16* q_buf = h_buf + (size_t)NB * CT;
  bf16* k_buf = q_buf + (size_t)NB * CT;
  bf16* v_buf = k_buf + (size_t)NB * CT;

  film_kernel<<<dim3(4, 16), 256, 0, stream>>>(emb, emb_w, emb_b, e_buf);
  gn_stats_kernel<<<dim3(B_ * G_), 256, 0, stream>>>(x, mean_buf, rstd_buf);
  for (int b0 = 0; b0 < B_; b0 += NB) {
    norm_film_kernel<<<dim3(NB * CT / 256), 256, 0, stream>>>(
        x, mean_buf, rstd_buf, gamma, beta, e_buf, h_buf, b0);
    qkv_gemm_kernel<<<dim3(16, 24, NB), 256, 0, stream>>>(h_buf, qkv_w, qkv_b,
                                                          q_buf, k_buf, v_buf);
    attn_kernel<<<dim3(128, NB * NH), 256, 0, stream>>>(q_buf, k_buf, v_buf,
                                                        h_buf);
    proj_kernel<<<dim3(16, 8, NB), 256, 0, stream>>>(h_buf, proj_w, proj_b, x,
                                                     out, b0);
  }
}

// Round 5
// 822.788 us; speedup vs baseline: 9.8202x; 9.8202x over previous
//
#include <hip/hip_runtime.h>
#include <hip/hip_bf16.h>

typedef __hip_bfloat16 bf16;
typedef __attribute__((ext_vector_type(8))) short short8;
typedef __attribute__((ext_vector_type(4))) float f32x4;

#define B_  16
#define C_  512
#define T_  1024
#define G_  32
#define CPG 16
#define E_  1024
#define NH  8
#define CH  64
#define CT  (C_ * T_)   // 524288 elements per batch

__device__ __forceinline__ float b2f(bf16 v) { return __bfloat162float(v); }
__device__ __forceinline__ bf16  f2b(float v) { return __float2bfloat16(v); }
__device__ __forceinline__ unsigned short fbits(float v) {
  bf16 t = f2b(v);
  return *reinterpret_cast<unsigned short*>(&t);
}

// ---------------------------------------------------------------------------
// K1: FiLM linear: e[b,j] = sum_i silu(emb[b,i]) * emb_w[j,i] + emb_b[j]
// ---------------------------------------------------------------------------
__global__ __launch_bounds__(256) void film_kernel(
    const float* __restrict__ emb, const float* __restrict__ emb_w,
    const float* __restrict__ emb_b, float* __restrict__ e_out) {
  __shared__ float se[E_];
  int b = blockIdx.y;
  int tid = threadIdx.x;
  for (int i = tid; i < E_; i += 256) {
    float v = emb[(size_t)b * E_ + i];
    se[i] = v / (1.f + __expf(-v));  // silu
  }
  __syncthreads();
  int j = blockIdx.x * 256 + tid;  // 0..1023 (= 2C)
  float acc = emb_b[j];
  for (int i = 0; i < E_; i++) acc += se[i] * emb_w[(size_t)j * E_ + i];
  e_out[b * (2 * C_) + j] = acc;
}

// ---------------------------------------------------------------------------
// K2: GroupNorm stats. One block per (b,g); 16384 contiguous f32.
// ---------------------------------------------------------------------------
__global__ __launch_bounds__(256) void gn_stats_kernel(
    const float* __restrict__ x, float* __restrict__ mean_buf,
    float* __restrict__ rstd_buf) {
  int bg = blockIdx.x;
  const float* base = x + (size_t)bg * (CPG * T_);
  int tid = threadIdx.x;
  float s = 0.f, sq = 0.f;
  for (int i = tid; i < CPG * T_; i += 256) {
    float v = base[i];
    s += v;
    sq += v * v;
  }
  for (int off = 32; off > 0; off >>= 1) {
    s += __shfl_down(s, off, 64);
    sq += __shfl_down(sq, off, 64);
  }
  __shared__ float ss[4], ssq[4];
  int wid = tid >> 6, lane = tid & 63;
  if (lane == 0) { ss[wid] = s; ssq[wid] = sq; }
  __syncthreads();
  if (tid == 0) {
    float S = ss[0] + ss[1] + ss[2] + ss[3];
    float Q = ssq[0] + ssq[1] + ssq[2] + ssq[3];
    const float inv_n = 1.f / (CPG * T_);
    float m = S * inv_n;
    float var = Q * inv_n - m * m;
    mean_buf[bg] = m;
    rstd_buf[bg] = rsqrtf(fmaxf(var, 0.f) + 1e-5f);
  }
}

// ---------------------------------------------------------------------------
// K3: normalize + FiLM -> h (bf16 [bl][c][t]). Chunked.
// ---------------------------------------------------------------------------
__global__ __launch_bounds__(256) void norm_film_kernel(
    const float* __restrict__ x, const float* __restrict__ mean_buf,
    const float* __restrict__ rstd_buf, const float* __restrict__ gamma,
    const float* __restrict__ beta, const float* __restrict__ e_buf,
    bf16* __restrict__ h, int b0) {
  int idx = blockIdx.x * 256 + threadIdx.x;
  int bc = idx >> 10;
  int c = bc & (C_ - 1);
  int bl = bc >> 9;
  int b = b0 + bl;
  int g = c >> 4;
  float m = mean_buf[b * G_ + g];
  float r = rstd_buf[b * G_ + g];
  float sc = e_buf[b * 2 * C_ + c];
  float sh = e_buf[b * 2 * C_ + C_ + c];
  size_t gidx = (size_t)b0 * CT + idx;
  float v = (x[gidx] - m) * r * gamma[c] + beta[c];
  v = v * (1.f + sc) + sh;
  h[idx] = f2b(v);
}

// ---------------------------------------------------------------------------
// K4: QKV GEMM. 64x64 tile, 256 threads, 4x4/thread, K-step 16.
// Lane map: tx = o-dim, ty = t-dim (so q/k stores are ch-coalesced).
// o-tile (64) lies in exactly one section/head: sec=(o0/64)%3, hd=o0/192.
// q,k -> [bhl][t][ch] bf16, pre-scaled by 64^-0.25.
// v   -> [bhl][ch][t] bf16 via LDS transpose (coalesced t-stores).
// ---------------------------------------------------------------------------
__global__ __launch_bounds__(256) void qkv_gemm_kernel(
    const bf16* __restrict__ h, const float* __restrict__ qkv_w,
    const float* __restrict__ qkv_b, bf16* __restrict__ qb,
    bf16* __restrict__ kb, bf16* __restrict__ vb) {
  __shared__ float Ws[16][65];             // [c_local][o_local]
  __shared__ float Hs[16][65];             // [c_local][t_local]
  __shared__ unsigned short St[64][72];    // v transpose staging [ch][t]
  int bl = blockIdx.z;
  int o0 = blockIdx.y * 64;
  int t0 = blockIdx.x * 64;
  int tid = threadIdx.x;
  int tx = tid & 15, ty = tid >> 4;        // tx -> o, ty -> t
  float acc[4][4] = {};                    // [i: t][j: o]
  const bf16* hb = h + (size_t)bl * CT;
  for (int k0 = 0; k0 < C_; k0 += 16) {
    int cl = tid & 15, ol = tid >> 4;
    for (int p = 0; p < 4; p++)
      Ws[cl][ol + 16 * p] = qkv_w[(size_t)(o0 + ol + 16 * p) * C_ + k0 + cl];
    int tl = tid & 63, ch = tid >> 6;
    for (int p = 0; p < 4; p++)
      Hs[ch + 4 * p][tl] = b2f(hb[(size_t)(k0 + ch + 4 * p) * T_ + t0 + tl]);
    __syncthreads();
    for (int kk = 0; kk < 16; kk++) {
      float ht[4], wo[4];
      for (int i = 0; i < 4; i++) ht[i] = Hs[kk][ty + 16 * i];
      for (int j = 0; j < 4; j++) wo[j] = Ws[kk][tx + 16 * j];
      for (int i = 0; i < 4; i++)
        for (int j = 0; j < 4; j++) acc[i][j] += ht[i] * wo[j];
    }
    __syncthreads();
  }
  const float s = 0.35355339059327373f;  // 64^-0.25
  int sec = (o0 >> 6) % 3;
  int hd = o0 / 192;
  if (sec < 2) {
    bf16* dst = (sec == 0) ? qb : kb;
    for (int i = 0; i < 4; i++) {
      int t = t0 + ty + 16 * i;
      size_t rowb = ((size_t)(bl * NH + hd) * T_ + t) * CH;
      for (int j = 0; j < 4; j++) {
        int ch = tx + 16 * j;
        dst[rowb + ch] = f2b((acc[i][j] + qkv_b[o0 + ch]) * s);
      }
    }
  } else {
    for (int i = 0; i < 4; i++)
      for (int j = 0; j < 4; j++) {
        int ch = tx + 16 * j;
        St[ch][ty + 16 * i] = fbits(acc[i][j] + qkv_b[o0 + ch]);
      }
    __syncthreads();
    int r = tid >> 2, cs = (tid & 3) * 16;
    size_t base = ((size_t)(bl * NH + hd) * CH + r) * T_ + t0 + cs;
    unsigned short* vg = (unsigned short*)vb;
    *(int4*)(vg + base) = *(const int4*)&St[r][cs];
    *(int4*)(vg + base + 8) = *(const int4*)&St[r][cs + 8];
  }
}

// ---------------------------------------------------------------------------
// K5: flash-style MFMA attention. Block = (bh, 64-query tile); 4 waves x 16 q
// rows. K/V 64-tiles in LDS; online softmax; P via per-wave LDS strip.
// q,k: [bh][t][ch]; v: [bh][ch][t]; out a: [bl][t][C] bf16.
// ---------------------------------------------------------------------------
__global__ __launch_bounds__(256) void attn_mfma_kernel(
    const bf16* __restrict__ qb, const bf16* __restrict__ kb,
    const bf16* __restrict__ vb, bf16* __restrict__ a) {
  __shared__ unsigned short Qs[64][72];
  __shared__ unsigned short Ks[64][72];
  __shared__ unsigned short Vt[64][72];     // [ch][s]
  __shared__ unsigned short Ps[4][16][72];  // per-wave P strip [m][s]
  int bh = blockIdx.y;
  int qt0 = blockIdx.x * 64;
  int tid = threadIdx.x;
  int wave = tid >> 6, lane = tid & 63;
  int col = lane & 15, quad = lane >> 4;
  int m0 = wave * 16;
  const unsigned short* qg = (const unsigned short*)qb;
  const unsigned short* kg = (const unsigned short*)kb;
  const unsigned short* vg = (const unsigned short*)vb;
  const size_t tmaj = (size_t)bh * T_ * CH;  // q/k base (t-major)
  const size_t cmaj = (size_t)bh * CH * T_;  // v base (ch-major)
  for (int i = tid; i < 512; i += 256) {
    int row = i >> 3, c8 = (i & 7) * 8;
    *(int4*)&Qs[row][c8] = *(const int4*)(qg + tmaj + (size_t)(qt0 + row) * CH + c8);
  }
  f32x4 Of[4] = {f32x4{0,0,0,0}, f32x4{0,0,0,0}, f32x4{0,0,0,0}, f32x4{0,0,0,0}};
  float m_r[4], l_r[4];
  for (int r = 0; r < 4; r++) { m_r[r] = -1e30f; l_r[r] = 0.f; }

  for (int s0 = 0; s0 < T_; s0 += 64) {
    __syncthreads();
    for (int i = tid; i < 512; i += 256) {
      int row = i >> 3, c8 = (i & 7) * 8;
      *(int4*)&Ks[row][c8] = *(const int4*)(kg + tmaj + (size_t)(s0 + row) * CH + c8);
      *(int4*)&Vt[row][c8] = *(const int4*)(vg + cmaj + (size_t)row * T_ + s0 + c8);
    }
    __syncthreads();
    // QK^T: S[m][n] = sum_ch Q[m][ch] K[n][ch]
    f32x4 Sf[4] = {f32x4{0,0,0,0}, f32x4{0,0,0,0}, f32x4{0,0,0,0}, f32x4{0,0,0,0}};
    for (int kc = 0; kc < 2; kc++) {
      short8 aq = *(const short8*)&Qs[m0 + col][kc * 32 + quad * 8];
      for (int nt = 0; nt < 4; nt++) {
        short8 bk = *(const short8*)&Ks[nt * 16 + col][kc * 32 + quad * 8];
        Sf[nt] = __builtin_amdgcn_mfma_f32_16x16x32_bf16(aq, bk, Sf[nt], 0, 0, 0);
      }
    }
    // online softmax (row r lives on 16 lanes sharing quad)
    float mx[4], al[4], rs[4];
    for (int r = 0; r < 4; r++)
      mx[r] = fmaxf(fmaxf(Sf[0][r], Sf[1][r]), fmaxf(Sf[2][r], Sf[3][r]));
    for (int off = 1; off < 16; off <<= 1)
      for (int r = 0; r < 4; r++) mx[r] = fmaxf(mx[r], __shfl_xor(mx[r], off));
    for (int r = 0; r < 4; r++) {
      float nm = fmaxf(m_r[r], mx[r]);
      al[r] = __expf(m_r[r] - nm);
      m_r[r] = nm;
      rs[r] = 0.f;
    }
    for (int nt = 0; nt < 4; nt++)
      for (int r = 0; r < 4; r++) {
        float p = __expf(Sf[nt][r] - m_r[r]);
        Sf[nt][r] = p;
        rs[r] += p;
      }
    for (int off = 1; off < 16; off <<= 1)
      for (int r = 0; r < 4; r++) rs[r] += __shfl_xor(rs[r], off);
    for (int r = 0; r < 4; r++) l_r[r] = l_r[r] * al[r] + rs[r];
    for (int nt = 0; nt < 4; nt++)
      for (int r = 0; r < 4; r++) Of[nt][r] *= al[r];
    // P: D-layout -> A-layout via per-wave LDS strip
    for (int nt = 0; nt < 4; nt++)
      for (int r = 0; r < 4; r++)
        Ps[wave][quad * 4 + r][nt * 16 + col] = fbits(Sf[nt][r]);
    // PV: O[m][ch] += sum_s P[m][s] V[s][ch]
    for (int kc = 0; kc < 2; kc++) {
      short8 pa = *(const short8*)&Ps[wave][col][kc * 32 + quad * 8];
      for (int nt = 0; nt < 4; nt++) {
        short8 bv = *(const short8*)&Vt[nt * 16 + col][kc * 32 + quad * 8];
        Of[nt] = __builtin_amdgcn_mfma_f32_16x16x32_bf16(pa, bv, Of[nt], 0, 0, 0);
      }
    }
  }
  // epilogue: a[bl][t][C], c = hd*64 + ch
  int bl = bh >> 3, hd = bh & 7;
  for (int r = 0; r < 4; r++) {
    float inv = 1.f / l_r[r];
    int t = qt0 + m0 + quad * 4 + r;
    size_t rb = ((size_t)bl * T_ + t) * C_ + hd * CH;
    for (int nt = 0; nt < 4; nt++)
      a[rb + nt * 16 + col] = f2b(Of[nt][r] * inv);
  }
}

// ---------------------------------------------------------------------------
// K6: proj GEMM + residual. a chunk-local [bl][t][C] bf16; x/out global fp32.
// ---------------------------------------------------------------------------
__global__ __launch_bounds__(256) void proj_kernel(
    const bf16* __restrict__ a, const float* __restrict__ proj_w,
    const float* __restrict__ proj_b, const float* __restrict__ x,
    float* __restrict__ out, int b0) {
  __shared__ float Ws[16][65];
  __shared__ float As[16][65];
  int bl = blockIdx.z;
  int b = b0 + bl;
  int o0 = blockIdx.y * 64;
  int t0 = blockIdx.x * 64;
  int tid = threadIdx.x;
  int tx = tid & 15, ty = tid >> 4;
  float acc[4][4] = {};
  const bf16* ab = a + (size_t)bl * CT;
  for (int k0 = 0; k0 < C_; k0 += 16) {
    int cl = tid & 15, ol = tid >> 4;
    for (int p = 0; p < 4; p++)
      Ws[cl][ol + 16 * p] = proj_w[(size_t)(o0 + ol + 16 * p) * C_ + k0 + cl];
    for (int p = 0; p < 4; p++) {
      int i = p * 256 + tid;
      int cl2 = i & 15, tl = i >> 4;  // a is [t][C]: consecutive tid -> consecutive c
      As[cl2][tl] = b2f(ab[(size_t)(t0 + tl) * C_ + k0 + cl2]);
    }
    __syncthreads();
    for (int kk = 0; kk < 16; kk++) {
      float wr[4], ar[4];
      for (int i = 0; i < 4; i++) wr[i] = Ws[kk][ty + 16 * i];
      for (int j = 0; j < 4; j++) ar[j] = As[kk][tx + 16 * j];
      for (int i = 0; i < 4; i++)
        for (int j = 0; j < 4; j++) acc[i][j] += wr[i] * ar[j];
    }
    __syncthreads();
  }
  for (int i = 0; i < 4; i++) {
    int o = o0 + ty + 16 * i;
    float bias = proj_b[o];
    for (int j = 0; j < 4; j++) {
      int t = t0 + tx + 16 * j;
      size_t idx = ((size_t)b * C_ + o) * T_ + t;
      out[idx] = x[idx] + acc[i][j] + bias;
    }
  }
}

// ---------------------------------------------------------------------------
extern "C" void kernel_launch(void* const* d_in, const int* in_sizes, int n_in,
                              void* d_out, int out_size, void* d_ws,
                              size_t ws_size, hipStream_t stream) {
  const float* x      = (const float*)d_in[0];
  const float* emb    = (const float*)d_in[1];
  const float* gamma  = (const float*)d_in[2];
  const float* beta   = (const float*)d_in[3];
  const float* emb_w  = (const float*)d_in[4];
  const float* emb_b  = (const float*)d_in[5];
  const float* qkv_w  = (const float*)d_in[6];
  const float* qkv_b  = (const float*)d_in[7];
  const float* proj_w = (const float*)d_in[8];
  const float* proj_b = (const float*)d_in[9];
  float* out = (float*)d_out;

  float* e_buf    = (float*)d_ws;                 // B*2C f32
  float* mean_buf = e_buf + B_ * 2 * C_;          // 512 f32
  float* rstd_buf = mean_buf + B_ * G_;           // 512 f32
  const size_t FIXED_BYTES = 131072;
  bf16* pool = (bf16*)((char*)d_ws + FIXED_BYTES);

  size_t avail = ws_size > FIXED_BYTES ? ws_size - FIXED_BYTES : 0;
  int NB = 16;
  while (NB > 1 && (size_t)4 * NB * CT * sizeof(bf16) > avail) NB >>= 1;

  bf16* h_buf = pool;                       // also 'a' (aliased after h consumed)
  bf16* q_buf = h_buf + (size_t)NB * CT;
  bf16* k_buf = q_buf + (size_t)NB * CT;
  bf16* v_buf = k_buf + (size_t)NB * CT;

  film_kernel<<<dim3(4, 16), 256, 0, stream>>>(emb, emb_w, emb_b, e_buf);
  gn_stats_kernel<<<dim3(B_ * G_), 256, 0, stream>>>(x, mean_buf, rstd_buf);
  for (int b0 = 0; b0 < B_; b0 += NB) {
    norm_film_kernel<<<dim3(NB * CT / 256), 256, 0, stream>>>(
        x, mean_buf, rstd_buf, gamma, beta, e_buf, h_buf, b0);
    qkv_gemm_kernel<<<dim3(16, 24, NB), 256, 0, stream>>>(h_buf, qkv_w, qkv_b,
                                                          q_buf, k_buf, v_buf);
    attn_mfma_kernel<<<dim3(16, NB * NH), 256, 0, stream>>>(q_buf, k_buf,
                                                            v_buf, h_buf);
    proj_kernel<<<dim3(16, 8, NB), 256, 0, stream>>>(h_buf, proj_w, proj_b, x,
                                                     out, b0);
  }
}

// Round 6
// 422.950 us; speedup vs baseline: 19.1038x; 1.9454x over previous
//
#include <hip/hip_runtime.h>
#include <hip/hip_bf16.h>

typedef __hip_bfloat16 bf16;
typedef __attribute__((ext_vector_type(8))) short short8;
typedef __attribute__((ext_vector_type(4))) float f32x4;
typedef __attribute__((ext_vector_type(4))) unsigned short us4;

#define B_  16
#define C_  512
#define T_  1024
#define G_  32
#define CPG 16
#define E_  1024
#define NH  8
#define CH  64
#define CT  (C_ * T_)   // 524288 elements per batch

__device__ __forceinline__ float b2f(bf16 v) { return __bfloat162float(v); }
__device__ __forceinline__ bf16  f2b(float v) { return __float2bfloat16(v); }
__device__ __forceinline__ unsigned short fbits(float v) {
  bf16 t = f2b(v);
  return *reinterpret_cast<unsigned short*>(&t);
}

// ---------------------------------------------------------------------------
// K1: FiLM linear: e[b,j] = sum_i silu(emb[b,i]) * emb_w[j,i] + emb_b[j]
// ---------------------------------------------------------------------------
__global__ __launch_bounds__(256) void film_kernel(
    const float* __restrict__ emb, const float* __restrict__ emb_w,
    const float* __restrict__ emb_b, float* __restrict__ e_out) {
  __shared__ float se[E_];
  int b = blockIdx.y;
  int tid = threadIdx.x;
  for (int i = tid; i < E_; i += 256) {
    float v = emb[(size_t)b * E_ + i];
    se[i] = v / (1.f + __expf(-v));  // silu
  }
  __syncthreads();
  int j = blockIdx.x * 256 + tid;  // 0..1023 (= 2C)
  float acc = emb_b[j];
  for (int i = 0; i < E_; i++) acc += se[i] * emb_w[(size_t)j * E_ + i];
  e_out[b * (2 * C_) + j] = acc;
}

// ---------------------------------------------------------------------------
// K2: GroupNorm stats. One block per (b,g); 16384 contiguous f32.
// ---------------------------------------------------------------------------
__global__ __launch_bounds__(256) void gn_stats_kernel(
    const float* __restrict__ x, float* __restrict__ mean_buf,
    float* __restrict__ rstd_buf) {
  int bg = blockIdx.x;
  const float* base = x + (size_t)bg * (CPG * T_);
  int tid = threadIdx.x;
  float s = 0.f, sq = 0.f;
  for (int i = tid; i < CPG * T_; i += 256) {
    float v = base[i];
    s += v;
    sq += v * v;
  }
  for (int off = 32; off > 0; off >>= 1) {
    s += __shfl_down(s, off, 64);
    sq += __shfl_down(sq, off, 64);
  }
  __shared__ float ss[4], ssq[4];
  int wid = tid >> 6, lane = tid & 63;
  if (lane == 0) { ss[wid] = s; ssq[wid] = sq; }
  __syncthreads();
  if (tid == 0) {
    float S = ss[0] + ss[1] + ss[2] + ss[3];
    float Q = ssq[0] + ssq[1] + ssq[2] + ssq[3];
    const float inv_n = 1.f / (CPG * T_);
    float m = S * inv_n;
    float var = Q * inv_n - m * m;
    mean_buf[bg] = m;
    rstd_buf[bg] = rsqrtf(fmaxf(var, 0.f) + 1e-5f);
  }
}

// ---------------------------------------------------------------------------
// K3: normalize + FiLM -> h as bf16 [bl][t][C] (t-major!) via LDS transpose.
// Block = 64c x 64t tile. Loads x coalesced along t, stores h coalesced
// along c. Per-c params staged in LDS.
// ---------------------------------------------------------------------------
__global__ __launch_bounds__(256) void norm_film_t_kernel(
    const float* __restrict__ x, const float* __restrict__ mean_buf,
    const float* __restrict__ rstd_buf, const float* __restrict__ gamma,
    const float* __restrict__ beta, const float* __restrict__ e_buf,
    bf16* __restrict__ h, int b0) {
  __shared__ unsigned short S[64][66];
  __shared__ float pm[64], pr[64], pa[64], pb[64];  // premixed per-c params
  int t0 = blockIdx.x * 64;
  int c0 = blockIdx.y * 64;
  int bl = blockIdx.z;
  int b = b0 + bl;
  int tid = threadIdx.x;
  if (tid < 64) {
    int c = c0 + tid;
    int g = c >> 4;
    float m = mean_buf[b * G_ + g];
    float r = rstd_buf[b * G_ + g];
    float sc = 1.f + e_buf[b * 2 * C_ + c];
    float sh = e_buf[b * 2 * C_ + C_ + c];
    float gmul = r * gamma[c] * sc;            // v = (x-m)*gmul + (beta*sc+sh)
    pm[tid] = m;
    pr[tid] = gmul;
    pa[tid] = beta[c] * sc + sh;
    pb[tid] = 0.f;
  }
  __syncthreads();
  const float* xb = x + ((size_t)b * C_ + c0) * T_ + t0;
  for (int p = 0; p < 16; p++) {
    int i = p * 256 + tid;
    int cl = i >> 6, tl = i & 63;
    float v = xb[(size_t)cl * T_ + tl];
    S[cl][tl] = fbits((v - pm[cl]) * pr[cl] + pa[cl]);
  }
  __syncthreads();
  bf16* hb = h + ((size_t)bl * T_ + t0) * C_ + c0;
  unsigned short* hg = (unsigned short*)hb;
  for (int p = 0; p < 16; p++) {
    int i = p * 256 + tid;
    int tr = i >> 6, cr = i & 63;
    hg[(size_t)tr * C_ + cr] = S[cr][tr];
  }
}

// ---------------------------------------------------------------------------
// K4: QKV GEMM via MFMA. Block = 64t x 64o tile, 4 waves (wave = 16 t-rows).
// A = h[t][c] (m=t), B = qkv_w[o][c] fp32->bf16 (n=o). K-chunks of 64.
// o-tile maps to one section/head: sec=(o0/64)%3, hd=o0/192.
// q,k -> [bh][t][ch] *64^-0.25; v -> [bh][ch][t] via LDS transpose.
// ---------------------------------------------------------------------------
__global__ __launch_bounds__(256) void qkv_gemm_mfma(
    const bf16* __restrict__ h, const float* __restrict__ qkv_w,
    const float* __restrict__ qkv_b, bf16* __restrict__ qb,
    bf16* __restrict__ kb, bf16* __restrict__ vb) {
  __shared__ unsigned short Hs[64][72];
  __shared__ unsigned short Ws[64][72];
  __shared__ unsigned short St[64][72];
  int bl = blockIdx.z;
  int o0 = blockIdx.y * 64;
  int t0 = blockIdx.x * 64;
  int tid = threadIdx.x;
  int wave = tid >> 6, lane = tid & 63;
  int col = lane & 15, quad = lane >> 4;
  int m0 = wave * 16;
  const unsigned short* hg = (const unsigned short*)h + (size_t)bl * T_ * C_;
  f32x4 acc[4] = {f32x4{0,0,0,0}, f32x4{0,0,0,0}, f32x4{0,0,0,0}, f32x4{0,0,0,0}};
  for (int c0 = 0; c0 < C_; c0 += 64) {
    __syncthreads();
    for (int i = tid; i < 512; i += 256) {
      int row = i >> 3, c8 = (i & 7) * 8;
      *(int4*)&Hs[row][c8] = *(const int4*)(hg + (size_t)(t0 + row) * C_ + c0 + c8);
    }
    for (int i = tid; i < 1024; i += 256) {
      int row = i >> 4, c4 = (i & 15) * 4;
      float4 wv = *(const float4*)(qkv_w + (size_t)(o0 + row) * C_ + c0 + c4);
      us4 pk = {fbits(wv.x), fbits(wv.y), fbits(wv.z), fbits(wv.w)};
      *(us4*)&Ws[row][c4] = pk;
    }
    __syncthreads();
    for (int ks = 0; ks < 2; ks++) {
      short8 ah = *(const short8*)&Hs[m0 + col][ks * 32 + quad * 8];
      for (int nt = 0; nt < 4; nt++) {
        short8 bw = *(const short8*)&Ws[nt * 16 + col][ks * 32 + quad * 8];
        acc[nt] = __builtin_amdgcn_mfma_f32_16x16x32_bf16(ah, bw, acc[nt], 0, 0, 0);
      }
    }
  }
  int sec = (o0 >> 6) % 3;
  int hd = o0 / 192;
  const float s = 0.35355339059327373f;  // 64^-0.25
  if (sec < 2) {
    bf16* dst = (sec == 0) ? qb : kb;
    size_t hb = (size_t)(bl * NH + hd) * T_ * CH;
    for (int r = 0; r < 4; r++) {
      int t = t0 + m0 + quad * 4 + r;
      for (int nt = 0; nt < 4; nt++) {
        int ch = nt * 16 + col;
        dst[hb + (size_t)t * CH + ch] = f2b((acc[nt][r] + qkv_b[o0 + ch]) * s);
      }
    }
  } else {
    for (int r = 0; r < 4; r++) {
      int tl = m0 + quad * 4 + r;
      for (int nt = 0; nt < 4; nt++) {
        int ch = nt * 16 + col;
        St[ch][tl] = fbits(acc[nt][r] + qkv_b[o0 + ch]);
      }
    }
    __syncthreads();
    int rr = tid >> 2, cs = (tid & 3) * 16;
    size_t base = ((size_t)(bl * NH + hd) * CH + rr) * T_ + t0 + cs;
    unsigned short* vg = (unsigned short*)vb;
    *(int4*)(vg + base) = *(const int4*)&St[rr][cs];
    *(int4*)(vg + base + 8) = *(const int4*)&St[rr][cs + 8];
  }
}

// ---------------------------------------------------------------------------
// K5: flash-style MFMA attention (unchanged from round 5).
// q,k: [bh][t][ch]; v: [bh][ch][t]; out a: [bl][t][C] bf16.
// ---------------------------------------------------------------------------
__global__ __launch_bounds__(256) void attn_mfma_kernel(
    const bf16* __restrict__ qb, const bf16* __restrict__ kb,
    const bf16* __restrict__ vb, bf16* __restrict__ a) {
  __shared__ unsigned short Qs[64][72];
  __shared__ unsigned short Ks[64][72];
  __shared__ unsigned short Vt[64][72];
  __shared__ unsigned short Ps[4][16][72];
  int bh = blockIdx.y;
  int qt0 = blockIdx.x * 64;
  int tid = threadIdx.x;
  int wave = tid >> 6, lane = tid & 63;
  int col = lane & 15, quad = lane >> 4;
  int m0 = wave * 16;
  const unsigned short* qg = (const unsigned short*)qb;
  const unsigned short* kg = (const unsigned short*)kb;
  const unsigned short* vg = (const unsigned short*)vb;
  const size_t tmaj = (size_t)bh * T_ * CH;
  const size_t cmaj = (size_t)bh * CH * T_;
  for (int i = tid; i < 512; i += 256) {
    int row = i >> 3, c8 = (i & 7) * 8;
    *(int4*)&Qs[row][c8] = *(const int4*)(qg + tmaj + (size_t)(qt0 + row) * CH + c8);
  }
  f32x4 Of[4] = {f32x4{0,0,0,0}, f32x4{0,0,0,0}, f32x4{0,0,0,0}, f32x4{0,0,0,0}};
  float m_r[4], l_r[4];
  for (int r = 0; r < 4; r++) { m_r[r] = -1e30f; l_r[r] = 0.f; }

  for (int s0 = 0; s0 < T_; s0 += 64) {
    __syncthreads();
    for (int i = tid; i < 512; i += 256) {
      int row = i >> 3, c8 = (i & 7) * 8;
      *(int4*)&Ks[row][c8] = *(const int4*)(kg + tmaj + (size_t)(s0 + row) * CH + c8);
      *(int4*)&Vt[row][c8] = *(const int4*)(vg + cmaj + (size_t)row * T_ + s0 + c8);
    }
    __syncthreads();
    f32x4 Sf[4] = {f32x4{0,0,0,0}, f32x4{0,0,0,0}, f32x4{0,0,0,0}, f32x4{0,0,0,0}};
    for (int kc = 0; kc < 2; kc++) {
      short8 aq = *(const short8*)&Qs[m0 + col][kc * 32 + quad * 8];
      for (int nt = 0; nt < 4; nt++) {
        short8 bk = *(const short8*)&Ks[nt * 16 + col][kc * 32 + quad * 8];
        Sf[nt] = __builtin_amdgcn_mfma_f32_16x16x32_bf16(aq, bk, Sf[nt], 0, 0, 0);
      }
    }
    float mx[4], al[4], rs[4];
    for (int r = 0; r < 4; r++)
      mx[r] = fmaxf(fmaxf(Sf[0][r], Sf[1][r]), fmaxf(Sf[2][r], Sf[3][r]));
    for (int off = 1; off < 16; off <<= 1)
      for (int r = 0; r < 4; r++) mx[r] = fmaxf(mx[r], __shfl_xor(mx[r], off));
    for (int r = 0; r < 4; r++) {
      float nm = fmaxf(m_r[r], mx[r]);
      al[r] = __expf(m_r[r] - nm);
      m_r[r] = nm;
      rs[r] = 0.f;
    }
    for (int nt = 0; nt < 4; nt++)
      for (int r = 0; r < 4; r++) {
        float p = __expf(Sf[nt][r] - m_r[r]);
        Sf[nt][r] = p;
        rs[r] += p;
      }
    for (int off = 1; off < 16; off <<= 1)
      for (int r = 0; r < 4; r++) rs[r] += __shfl_xor(rs[r], off);
    for (int r = 0; r < 4; r++) l_r[r] = l_r[r] * al[r] + rs[r];
    for (int nt = 0; nt < 4; nt++)
      for (int r = 0; r < 4; r++) Of[nt][r] *= al[r];
    for (int nt = 0; nt < 4; nt++)
      for (int r = 0; r < 4; r++)
        Ps[wave][quad * 4 + r][nt * 16 + col] = fbits(Sf[nt][r]);
    for (int kc = 0; kc < 2; kc++) {
      short8 pa = *(const short8*)&Ps[wave][col][kc * 32 + quad * 8];
      for (int nt = 0; nt < 4; nt++) {
        short8 bv = *(const short8*)&Vt[nt * 16 + col][kc * 32 + quad * 8];
        Of[nt] = __builtin_amdgcn_mfma_f32_16x16x32_bf16(pa, bv, Of[nt], 0, 0, 0);
      }
    }
  }
  int bl = bh >> 3, hd = bh & 7;
  for (int r = 0; r < 4; r++) {
    float inv = 1.f / l_r[r];
    int t = qt0 + m0 + quad * 4 + r;
    size_t rb = ((size_t)bl * T_ + t) * C_ + hd * CH;
    for (int nt = 0; nt < 4; nt++)
      a[rb + nt * 16 + col] = f2b(Of[nt][r] * inv);
  }
}

// ---------------------------------------------------------------------------
// K6: proj GEMM + residual via MFMA. Block = 64o x 64t, 4 waves (16 o-rows).
// A = proj_w[o][c] fp32->bf16 (m=o), B = a[t][c] (n=t). D cols = consecutive
// t -> coalesced fp32 x-read / out-write.
// ---------------------------------------------------------------------------
__global__ __launch_bounds__(256) void proj_mfma(
    const bf16* __restrict__ a, const float* __restrict__ proj_w,
    const float* __restrict__ proj_b, const float* __restrict__ x,
    float* __restrict__ out, int b0) {
  __shared__ unsigned short As[64][72];
  __shared__ unsigned short Ws[64][72];
  int bl = blockIdx.z;
  int b = b0 + bl;
  int o0 = blockIdx.y * 64;
  int t0 = blockIdx.x * 64;
  int tid = threadIdx.x;
  int wave = tid >> 6, lane = tid & 63;
  int col = lane & 15, quad = lane >> 4;
  int m0 = wave * 16;
  const unsigned short* ag = (const unsigned short*)a + (size_t)bl * T_ * C_;
  f32x4 acc[4] = {f32x4{0,0,0,0}, f32x4{0,0,0,0}, f32x4{0,0,0,0}, f32x4{0,0,0,0}};
  for (int c0 = 0; c0 < C_; c0 += 64) {
    __syncthreads();
    for (int i = tid; i < 512; i += 256) {
      int row = i >> 3, c8 = (i & 7) * 8;
      *(int4*)&As[row][c8] = *(const int4*)(ag + (size_t)(t0 + row) * C_ + c0 + c8);
    }
    for (int i = tid; i < 1024; i += 256) {
      int row = i >> 4, c4 = (i & 15) * 4;
      float4 wv = *(const float4*)(proj_w + (size_t)(o0 + row) * C_ + c0 + c4);
      us4 pk = {fbits(wv.x), fbits(wv.y), fbits(wv.z), fbits(wv.w)};
      *(us4*)&Ws[row][c4] = pk;
    }
    __syncthreads();
    for (int ks = 0; ks < 2; ks++) {
      short8 aw = *(const short8*)&Ws[m0 + col][ks * 32 + quad * 8];
      for (int nt = 0; nt < 4; nt++) {
        short8 ba = *(const short8*)&As[nt * 16 + col][ks * 32 + quad * 8];
        acc[nt] = __builtin_amdgcn_mfma_f32_16x16x32_bf16(aw, ba, acc[nt], 0, 0, 0);
      }
    }
  }
  for (int r = 0; r < 4; r++) {
    int o = o0 + m0 + quad * 4 + r;
    float bias = proj_b[o];
    size_t rowb = ((size_t)b * C_ + o) * T_ + t0;
    for (int nt = 0; nt < 4; nt++) {
      int t = nt * 16 + col;
      out[rowb + t] = x[rowb + t] + acc[nt][r] + bias;
    }
  }
}

// ---------------------------------------------------------------------------
extern "C" void kernel_launch(void* const* d_in, const int* in_sizes, int n_in,
                              void* d_out, int out_size, void* d_ws,
                              size_t ws_size, hipStream_t stream) {
  const float* x      = (const float*)d_in[0];
  const float* emb    = (const float*)d_in[1];
  const float* gamma  = (const float*)d_in[2];
  const float* beta   = (const float*)d_in[3];
  const float* emb_w  = (const float*)d_in[4];
  const float* emb_b  = (const float*)d_in[5];
  const float* qkv_w  = (const float*)d_in[6];
  const float* qkv_b  = (const float*)d_in[7];
  const float* proj_w = (const float*)d_in[8];
  const float* proj_b = (const float*)d_in[9];
  float* out = (float*)d_out;

  float* e_buf    = (float*)d_ws;                 // B*2C f32
  float* mean_buf = e_buf + B_ * 2 * C_;          // 512 f32
  float* rstd_buf = mean_buf + B_ * G_;           // 512 f32
  const size_t FIXED_BYTES = 131072;
  bf16* pool = (bf16*)((char*)d_ws + FIXED_BYTES);

  size_t avail = ws_size > FIXED_BYTES ? ws_size - FIXED_BYTES : 0;
  int NB = 16;
  while (NB > 1 && (size_t)4 * NB * CT * sizeof(bf16) > avail) NB >>= 1;

  bf16* h_buf = pool;                       // also 'a' (aliased after h consumed)
  bf16* q_buf = h_buf + (size_t)NB * CT;
  bf16* k_buf = q_buf + (size_t)NB * CT;
  bf16* v_buf = k_buf + (size_t)NB * CT;

  film_kernel<<<dim3(4, 16), 256, 0, stream>>>(emb, emb_w, emb_b, e_buf);
  gn_stats_kernel<<<dim3(B_ * G_), 256, 0, stream>>>(x, mean_buf, rstd_buf);
  for (int b0 = 0; b0 < B_; b0 += NB) {
    norm_film_t_kernel<<<dim3(16, 8, NB), 256, 0, stream>>>(
        x, mean_buf, rstd_buf, gamma, beta, e_buf, h_buf, b0);
    qkv_gemm_mfma<<<dim3(16, 24, NB), 256, 0, stream>>>(h_buf, qkv_w, qkv_b,
                                                        q_buf, k_buf, v_buf);
    attn_mfma_kernel<<<dim3(16, NB * NH), 256, 0, stream>>>(q_buf, k_buf,
                                                            v_buf, h_buf);
    proj_mfma<<<dim3(16, 8, NB), 256, 0, stream>>>(h_buf, proj_w, proj_b, x,
                                                   out, b0);
  }
}